// Round 1
// baseline (964.257 us; speedup 1.0000x reference)
//
#include <hip/hip_runtime.h>
#include <math.h>

typedef _Float16 half8  __attribute__((ext_vector_type(8)));
typedef _Float16 half2v __attribute__((ext_vector_type(2)));
typedef float    floatx4 __attribute__((ext_vector_type(4)));

// ---------------------------------------------------------------------------
// K1: segment boundaries. seg_ids sorted, every id in [0,G) present.
// seg_start[g] = first row of segment g; seg_start[G] = N.
// ---------------------------------------------------------------------------
__global__ void seg_bounds_kernel(const int* __restrict__ seg,
                                  int* __restrict__ seg_start, int N, int G) {
    int i = blockIdx.x * 256 + threadIdx.x;
    if (i >= N) return;
    int s = seg[i];
    if (i == 0 || s != seg[i - 1]) seg_start[s] = i;
    if (i == N - 1) seg_start[G] = N;
}

__device__ inline half8 pack8(float4 a, float4 b) {
    half8 r;
    r[0] = (_Float16)a.x; r[1] = (_Float16)a.y; r[2] = (_Float16)a.z; r[3] = (_Float16)a.w;
    r[4] = (_Float16)b.x; r[5] = (_Float16)b.y; r[6] = (_Float16)b.z; r[7] = (_Float16)b.w;
    return r;
}

// ---------------------------------------------------------------------------
// K2: fused  keys-GEMM + q-GEMM + per-segment softmax + weighted sum.
// Block = 256 threads (4 waves). Wave owns 8 consecutive segments.
// MFMA 16x16x32 f16. Wk lives in 128 VGPRs per lane (full matrix / wave).
// Verified fragment layouts (learn_hip m89/m120):
//   A[m=lane&15][k=quad*8+j], B[n=lane&15][k=quad*8+j] (B^T rows),
//   C: col = lane&15 (n), row = quad*4 + reg (m).
// ---------------------------------------------------------------------------
__global__ __launch_bounds__(256, 2) void fused_attn_kernel(
    const float* __restrict__ emb, const int* __restrict__ seg_start,
    const float* __restrict__ Wq, const float* __restrict__ bq,
    const float* __restrict__ Wk, const float* __restrict__ bk,
    float* __restrict__ out)
{
    // per-wave buffers; row stride 136 halves (=272B) to spread LDS banks
    __shared__ alignas(16) _Float16 keys_lds[4][16][136];
    __shared__ alignas(16) _Float16 q_lds[4][8][136];
    __shared__ float L_lds[4][16];
    __shared__ int   nt_lds[4];

    const int wave = threadIdx.x >> 6;
    const int lane = threadIdx.x & 63;
    const int m    = lane & 15;
    const int quad = lane >> 4;

    const int g0 = blockIdx.x * 32 + wave * 8;   // first segment of this wave
    const int s0 = seg_start[g0];
    const int e0 = seg_start[g0 + 8];

    // uniform segment bounds for logit extraction (constant-indexed only)
    int sb[9];
#pragma unroll
    for (int i = 0; i <= 8; ++i) sb[i] = seg_start[g0 + i];

    // biases for this lane's column slots (dim = 16c + m)
    float bqv[8], bkv[8];
#pragma unroll
    for (int c = 0; c < 8; ++c) { bqv[c] = bq[16 * c + m]; bkv[c] = bk[16 * c + m]; }

    // -------- phase 1: q for the wave's 8 segments ------------------------
    {
        int  qm  = (m < 8) ? m : 7;                    // dup row for m>=8
        long qrow = (long)seg_start[g0 + qm + 1] - 1;  // last row of segment qm
        half8 aq[4];
#pragma unroll
        for (int kq = 0; kq < 4; ++kq) {
            const float4* p = (const float4*)(emb + qrow * 128 + kq * 32 + quad * 8);
            aq[kq] = pack8(p[0], p[1]);
        }
#pragma unroll
        for (int c = 0; c < 8; ++c) {
            floatx4 acc = {bqv[c], bqv[c], bqv[c], bqv[c]};
#pragma unroll
            for (int kq = 0; kq < 4; ++kq) {
                const float4* wp = (const float4*)(Wq + (16 * c + m) * 128 + kq * 32 + quad * 8);
                half8 bf = pack8(wp[0], wp[1]);
                acc = __builtin_amdgcn_mfma_f32_16x16x32_f16(aq[kq], bf, acc, 0, 0, 0);
            }
            if (quad < 2) {                            // rows 0..7 = segments
#pragma unroll
                for (int r = 0; r < 4; ++r)
                    q_lds[wave][quad * 4 + r][16 * c + m] = (_Float16)acc[r];
            }
        }
    }

    // -------- phase 2: all of Wk into registers (f16 B-fragments) ---------
    half8 wkf[8][4];
#pragma unroll
    for (int c = 0; c < 8; ++c)
#pragma unroll
        for (int kq = 0; kq < 4; ++kq) {
            const float4* wp = (const float4*)(Wk + (16 * c + m) * 128 + kq * 32 + quad * 8);
            wkf[c][kq] = pack8(wp[0], wp[1]);
        }

    int my_nt = (e0 - s0 + 15) >> 4;
    if (lane == 0) nt_lds[wave] = my_nt;
    __syncthreads();                                    // also publishes q_lds
    const int mtiles = max(max(nt_lds[0], nt_lds[1]), max(nt_lds[2], nt_lds[3]));

    // online-softmax state (segments arrive in sorted order -> scalar state)
    int   g = g0;
    int   cur_end = sb[1];
    float run_m = -INFINITY, run_d = 0.f, acc0 = 0.f, acc1 = 0.f;

    for (int tt = 0; tt < mtiles; ++tt) {
        const int  t      = s0 + tt * 16;
        const bool active = t < e0;
        const int  cnt    = active ? min(16, e0 - t) : 0;

        if (active) {
            // A fragments: 16 emb rows (tail rows clamped -> harmless dups)
            long row = min(t + m, e0 - 1);
            half8 ak[4];
#pragma unroll
            for (int kq = 0; kq < 4; ++kq) {
                const float4* p = (const float4*)(emb + row * 128 + kq * 32 + quad * 8);
                ak[kq] = pack8(p[0], p[1]);
            }
            // keys = emb @ Wk^T + bk   (bias folded into acc init)
#pragma unroll
            for (int c = 0; c < 8; ++c) {
                floatx4 acc = {bkv[c], bkv[c], bkv[c], bkv[c]};
#pragma unroll
                for (int kq = 0; kq < 4; ++kq)
                    acc = __builtin_amdgcn_mfma_f32_16x16x32_f16(ak[kq], wkf[c][kq], acc, 0, 0, 0);
#pragma unroll
                for (int r = 0; r < 4; ++r)
                    keys_lds[wave][quad * 4 + r][16 * c + m] = (_Float16)acc[r];
            }
        }
        __syncthreads();   // keys_lds visible (uniform barrier: outside 'active')

        if (active) {
            // logits: L[r][s] = keys[r] . q[s]  via one MFMA col-tile
            floatx4 lacc = {0.f, 0.f, 0.f, 0.f};
#pragma unroll
            for (int kq = 0; kq < 4; ++kq) {
                half8 af = *(const half8*)&keys_lds[wave][m][kq * 32 + quad * 8];
                half8 bf = *(const half8*)&q_lds[wave][m & 7][kq * 32 + quad * 8];
                lacc = __builtin_amdgcn_mfma_f32_16x16x32_f16(af, bf, lacc, 0, 0, 0);
            }
            // extract L[r][seg(r)]: exactly one lane (m == local seg) writes
#pragma unroll
            for (int r = 0; r < 4; ++r) {
                int rowc = min(t + quad * 4 + r, e0 - 1);
                int sl = 0;
#pragma unroll
                for (int i = 1; i < 8; ++i) sl += (rowc >= sb[i]) ? 1 : 0;
                if (m == sl) L_lds[wave][quad * 4 + r] = lacc[r];
            }
        }
        __syncthreads();   // L_lds visible

        // -------- serial row phase: online softmax + weighted key sum -----
        for (int rl = 0; rl < cnt; ++rl) {
            int row = t + rl;
            while (row >= cur_end) {       // wave-uniform segment boundary
                float inv = 1.0f / run_d;
                float2 o; o.x = acc0 * inv; o.y = acc1 * inv;
                *(float2*)(out + (long)g * 128 + 2 * lane) = o;
                ++g;
                cur_end = seg_start[g + 1];
                run_m = -INFINITY; run_d = 0.f; acc0 = 0.f; acc1 = 0.f;
            }
            float logit = L_lds[wave][rl];                       // broadcast
            half2v kv = *(const half2v*)&keys_lds[wave][rl][2 * lane];
            float k0 = (float)kv[0], k1 = (float)kv[1];
            float nm = fmaxf(run_m, logit);
            float sc = __expf(run_m - nm);   // expf(-inf)=0 handles first row
            float e  = __expf(logit - nm);
            run_d = run_d * sc + e;
            acc0  = acc0 * sc + e * k0;
            acc1  = acc1 * sc + e * k1;
            run_m = nm;
        }
    }
    // finalize the wave's last segment
    {
        float inv = 1.0f / run_d;
        float2 o; o.x = acc0 * inv; o.y = acc1 * inv;
        *(float2*)(out + (long)g * 128 + 2 * lane) = o;
    }
}

// ---------------------------------------------------------------------------
extern "C" void kernel_launch(void* const* d_in, const int* in_sizes, int n_in,
                              void* d_out, int out_size, void* d_ws, size_t ws_size,
                              hipStream_t stream) {
    const float* emb = (const float*)d_in[0];
    const int*   seg = (const int*)d_in[1];
    const float* Wq  = (const float*)d_in[2];
    const float* bq  = (const float*)d_in[3];
    const float* Wk  = (const float*)d_in[4];
    const float* bk  = (const float*)d_in[5];
    float* out = (float*)d_out;

    const int N = in_sizes[1];          // number of rows / seg ids
    const int G = out_size / 128;       // number of segments

    int* seg_start = (int*)d_ws;        // (G+1) ints

    seg_bounds_kernel<<<(N + 255) / 256, 256, 0, stream>>>(seg, seg_start, N, G);
    // G = 100000 is divisible by 32 (8 segs/wave * 4 waves/block)
    fused_attn_kernel<<<G / 32, 256, 0, stream>>>(emb, seg_start, Wq, bq, Wk, bk, out);
}

// Round 2
// 803.359 us; speedup vs baseline: 1.2003x; 1.2003x over previous
//
#include <hip/hip_runtime.h>
#include <math.h>

typedef _Float16 half8  __attribute__((ext_vector_type(8)));
typedef _Float16 half2v __attribute__((ext_vector_type(2)));
typedef float    floatx4 __attribute__((ext_vector_type(4)));

// wave-local LDS fence: all our LDS traffic is intra-wave (one wave per block),
// DS ops complete in order per wave -> s_waitcnt lgkmcnt(0) is a full fence.
#define LGKM_FENCE() asm volatile("s_waitcnt lgkmcnt(0)" ::: "memory")

// ---------------------------------------------------------------------------
// K1: segment boundaries. seg_ids sorted, every id in [0,G) present.
// ---------------------------------------------------------------------------
__global__ void seg_bounds_kernel(const int* __restrict__ seg,
                                  int* __restrict__ seg_start, int N, int G) {
    int i = blockIdx.x * 256 + threadIdx.x;
    if (i >= N) return;
    int s = seg[i];
    if (i == 0 || s != seg[i - 1]) seg_start[s] = i;
    if (i == N - 1) seg_start[G] = N;
}

__device__ inline half8 pack8(float4 a, float4 b) {
    half8 r;
    r[0] = (_Float16)a.x; r[1] = (_Float16)a.y; r[2] = (_Float16)a.z; r[3] = (_Float16)a.w;
    r[4] = (_Float16)b.x; r[5] = (_Float16)b.y; r[6] = (_Float16)b.z; r[7] = (_Float16)b.w;
    return r;
}

// ---------------------------------------------------------------------------
// K2: fused keys-GEMM + q-GEMM + per-segment softmax + weighted sum.
// ONE WAVE PER BLOCK (64 threads), 8 consecutive segments per wave.
// No __syncthreads anywhere: waves fully decoupled, LDS fenced wave-locally.
// Wk resident in 128 VGPRs; emb tiles software-pipelined (prefetch t+1).
// MFMA 16x16x32 f16 layouts (verified m89/m120):
//   A[m=lane&15][k=quad*8+j], B[n=lane&15][k=quad*8+j], C: col=lane&15,
//   row=quad*4+reg.
// ---------------------------------------------------------------------------
__global__ __launch_bounds__(64, 2) void fused_attn_kernel(
    const float* __restrict__ emb, const int* __restrict__ seg_start,
    const float* __restrict__ Wq, const float* __restrict__ bq,
    const float* __restrict__ Wk, const float* __restrict__ bk,
    float* __restrict__ out)
{
    __shared__ alignas(16) _Float16 keys_lds[16][136];  // stride 136h = 272B
    __shared__ alignas(16) _Float16 q_lds[8][136];
    __shared__ alignas(16) float    L_lds[16];

    const int lane = threadIdx.x;      // 0..63 (one wave)
    const int m    = lane & 15;
    const int quad = lane >> 4;

    const int g0 = blockIdx.x * 8;     // first of this wave's 8 segments
    const int s0 = seg_start[g0];
    const int e0 = seg_start[g0 + 8];

    // wave-uniform segment bounds (constant-indexed only)
    int sb[9];
#pragma unroll
    for (int i = 0; i <= 8; ++i) sb[i] = seg_start[g0 + i];

    // bk for this lane's column slots (dim = 16c + m)
    float bkv[8];
#pragma unroll
    for (int c = 0; c < 8; ++c) bkv[c] = bk[16 * c + m];

    // -------- phase 1: q for the 8 segments (one MFMA col pass) -----------
    {
        int  qm   = (m < 8) ? m : 7;                   // dup row for m>=8
        long qrow = (long)seg_start[g0 + qm + 1] - 1;  // last row of segment qm
        half8 aq[4];
#pragma unroll
        for (int kq = 0; kq < 4; ++kq) {
            const float4* p = (const float4*)(emb + qrow * 128 + kq * 32 + quad * 8);
            aq[kq] = pack8(p[0], p[1]);
        }
#pragma unroll
        for (int c = 0; c < 8; ++c) {
            float bqc = bq[16 * c + m];
            floatx4 acc = {bqc, bqc, bqc, bqc};
#pragma unroll
            for (int kq = 0; kq < 4; ++kq) {
                const float4* wp = (const float4*)(Wq + (16 * c + m) * 128 + kq * 32 + quad * 8);
                half8 bf = pack8(wp[0], wp[1]);
                acc = __builtin_amdgcn_mfma_f32_16x16x32_f16(aq[kq], bf, acc, 0, 0, 0);
            }
            if (quad < 2) {                            // rows 0..7 = segments
#pragma unroll
                for (int r = 0; r < 4; ++r)
                    q_lds[quad * 4 + r][16 * c + m] = (_Float16)acc[r];
            }
        }
    }
    LGKM_FENCE();   // publish q_lds to the wave

    // -------- phase 2: all of Wk into registers (f16 B-fragments) ---------
    half8 wkf[8][4];
#pragma unroll
    for (int c = 0; c < 8; ++c)
#pragma unroll
        for (int kq = 0; kq < 4; ++kq) {
            const float4* wp = (const float4*)(Wk + (16 * c + m) * 128 + kq * 32 + quad * 8);
            wkf[c][kq] = pack8(wp[0], wp[1]);
        }

    const int nt = (e0 - s0 + 15) >> 4;

    // preload tile 0 raw (software pipeline stage)
    float4 pre[8];
    {
        long prow = (long)min(s0 + m, e0 - 1);
#pragma unroll
        for (int kq = 0; kq < 4; ++kq) {
            const float4* p = (const float4*)(emb + prow * 128 + kq * 32 + quad * 8);
            pre[2 * kq] = p[0]; pre[2 * kq + 1] = p[1];
        }
    }

    // online-softmax state (segments arrive sorted -> scalar state)
    int   g = g0;
    int   cur_end = sb[1];
    float run_m = -INFINITY, run_d = 0.f, acc0 = 0.f, acc1 = 0.f;

    for (int tt = 0; tt < nt; ++tt) {
        const int t   = s0 + tt * 16;
        const int cnt = min(16, e0 - t);

        // consume prefetched raw -> A fragments
        half8 ak[4];
#pragma unroll
        for (int kq = 0; kq < 4; ++kq)
            ak[kq] = pack8(pre[2 * kq], pre[2 * kq + 1]);

        // prefetch next tile (overlaps MFMA + softmax below)
        if (tt + 1 < nt) {
            long nrow = (long)min(t + 16 + m, e0 - 1);
#pragma unroll
            for (int kq = 0; kq < 4; ++kq) {
                const float4* p = (const float4*)(emb + nrow * 128 + kq * 32 + quad * 8);
                pre[2 * kq] = p[0]; pre[2 * kq + 1] = p[1];
            }
        }

        // keys = emb @ Wk^T + bk (bias folded into acc init)
#pragma unroll
        for (int c = 0; c < 8; ++c) {
            floatx4 acc = {bkv[c], bkv[c], bkv[c], bkv[c]};
#pragma unroll
            for (int kq = 0; kq < 4; ++kq)
                acc = __builtin_amdgcn_mfma_f32_16x16x32_f16(ak[kq], wkf[c][kq], acc, 0, 0, 0);
#pragma unroll
            for (int r = 0; r < 4; ++r)
                keys_lds[quad * 4 + r][16 * c + m] = (_Float16)acc[r];
        }
        LGKM_FENCE();   // keys_lds visible to the wave

        // logits: L[r][s] = keys[r] . q[s] via one MFMA col-tile
        floatx4 lacc = {0.f, 0.f, 0.f, 0.f};
#pragma unroll
        for (int kq = 0; kq < 4; ++kq) {
            half8 af = *(const half8*)&keys_lds[m][kq * 32 + quad * 8];
            half8 bf = *(const half8*)&q_lds[m & 7][kq * 32 + quad * 8];
            lacc = __builtin_amdgcn_mfma_f32_16x16x32_f16(af, bf, lacc, 0, 0, 0);
        }
        // extract L[r][seg(r)]: exactly one lane (m == local seg) writes
#pragma unroll
        for (int r = 0; r < 4; ++r) {
            int rowc = min(t + quad * 4 + r, e0 - 1);
            int sl = 0;
#pragma unroll
            for (int i = 1; i < 8; ++i) sl += (rowc >= sb[i]) ? 1 : 0;
            if (m == sl) L_lds[quad * 4 + r] = lacc[r];
        }
        LGKM_FENCE();   // L_lds visible

        // hoist ALL serial-phase LDS reads -> batch-pipelined, then pure VALU
        float lg[16];
#pragma unroll
        for (int i = 0; i < 4; ++i) {
            float4 v = *(const float4*)&L_lds[4 * i];   // broadcast reads
            lg[4 * i] = v.x; lg[4 * i + 1] = v.y; lg[4 * i + 2] = v.z; lg[4 * i + 3] = v.w;
        }
        half2v kv[16];
#pragma unroll
        for (int r = 0; r < 16; ++r)
            kv[r] = *(const half2v*)&keys_lds[r][2 * lane];

        // serial row phase: online softmax + weighted key sum (registers only)
#pragma unroll
        for (int rl = 0; rl < 16; ++rl) {
            if (rl < cnt) {                      // wave-uniform guard
                int row = t + rl;
                while (row >= cur_end) {         // wave-uniform boundary
                    float inv = 1.0f / run_d;
                    float2 o; o.x = acc0 * inv; o.y = acc1 * inv;
                    *(float2*)(out + (long)g * 128 + 2 * lane) = o;
                    ++g;
                    cur_end = seg_start[g + 1];
                    run_m = -INFINITY; run_d = 0.f; acc0 = 0.f; acc1 = 0.f;
                }
                float logit = lg[rl];
                float k0 = (float)kv[rl][0], k1 = (float)kv[rl][1];
                float nm = fmaxf(run_m, logit);
                float sc = __expf(run_m - nm);   // expf(-inf)=0 handles first row
                float e  = __expf(logit - nm);
                run_d = run_d * sc + e;
                acc0  = acc0 * sc + e * k0;
                acc1  = acc1 * sc + e * k1;
                run_m = nm;
            }
        }
    }
    // finalize the wave's last segment
    {
        float inv = 1.0f / run_d;
        float2 o; o.x = acc0 * inv; o.y = acc1 * inv;
        *(float2*)(out + (long)g * 128 + 2 * lane) = o;
    }
}

// ---------------------------------------------------------------------------
extern "C" void kernel_launch(void* const* d_in, const int* in_sizes, int n_in,
                              void* d_out, int out_size, void* d_ws, size_t ws_size,
                              hipStream_t stream) {
    const float* emb = (const float*)d_in[0];
    const int*   seg = (const int*)d_in[1];
    const float* Wq  = (const float*)d_in[2];
    const float* bq  = (const float*)d_in[3];
    const float* Wk  = (const float*)d_in[4];
    const float* bk  = (const float*)d_in[5];
    float* out = (float*)d_out;

    const int N = in_sizes[1];          // number of rows / seg ids
    const int G = out_size / 128;       // number of segments

    int* seg_start = (int*)d_ws;        // (G+1) ints

    seg_bounds_kernel<<<(N + 255) / 256, 256, 0, stream>>>(seg, seg_start, N, G);
    // G = 100000 divisible by 8 (8 segments per wave, 1 wave per block)
    fused_attn_kernel<<<G / 8, 64, 0, stream>>>(emb, seg_start, Wq, bq, Wk, bk, out);
}